// Round 1
// baseline (2494.769 us; speedup 1.0000x reference)
//
#include <hip/hip_runtime.h>
#include <hip/hip_bf16.h>
#include <math.h>

#define IN_CHN 128
#define OUT_CHN 128
#define TDIM 64
#define KD 192        // IN_CHN + TDIM
#define TM 32         // edges per tile
#define MPAD 36       // padded stride (floats): 144 B, 16B-aligned rows

static __device__ __forceinline__ unsigned short f2bf(float f) {
    unsigned int u = __float_as_uint(f);
    unsigned int r = (u + 0x7FFFu + ((u >> 16) & 1u)) >> 16;  // RNE
    return (unsigned short)r;
}
static __device__ __forceinline__ float bf2f(unsigned short b) {
    return __uint_as_float(((unsigned int)b) << 16);
}

static __device__ __forceinline__ void atomicMaxF(float* addr, float v) {
    if (v >= 0.0f) atomicMax((int*)addr, __float_as_int(v));
    else           atomicMin((unsigned int*)addr, (unsigned int)__float_as_int(v));
}

__global__ __launch_bounds__(256) void init_nodes(float* nm, float* den, int n) {
    int i = blockIdx.x * 256 + threadIdx.x;
    if (i < n) { nm[i] = -INFINITY; den[i] = 0.0f; }
}

// Persistent-block GEMM: h = tanh([x[src], te] @ W^T + b), alpha = h . attn
// W^T staged once per block in LDS (96 KB); msg tile = 32 edges (27 KB).
__global__ __launch_bounds__(256) void gemm_alpha(
    const float* __restrict__ x, const int* __restrict__ ei,
    const float* __restrict__ et, const float* __restrict__ freqs,
    const float* __restrict__ lw, const float* __restrict__ lb,
    const float* __restrict__ attn,
    unsigned short* __restrict__ h_ws, float* __restrict__ alpha,
    float* __restrict__ node_max, int E, int n_tiles)
{
    __shared__ float smem[24576 + KD * MPAD];   // 125,952 B
    float* Wt  = smem;          // Wt[k][c] = lw[c][k], [192][128]
    float* msg = smem + 24576;  // msg[k][edge], [192][36]

    const int tid = threadIdx.x;

    // Load W transposed into LDS (once per block).
    for (int i = tid; i < 24576; i += 256) {
        int k = i >> 7, c = i & 127;
        Wt[i] = lw[c * KD + k];
    }

    const int tx = tid & 31;        // channel group: c0 = tx*4
    const int ty = tid >> 5;        // edge group:    m0 = ty*4  (ty in [0,8))

    for (int tile = blockIdx.x; tile < n_tiles; tile += gridDim.x) {
        const int e0 = tile * TM;
        __syncthreads();   // msg readers from previous tile done

        // ---- stage msg tile: [k][edge] ----
        {
            const int el = tid & 31;       // edge within tile
            const int q  = tid >> 5;       // [0,8): feature block q*16..q*16+15
            int eg = e0 + el;
            int egc = eg < E ? eg : E - 1;
            int s = ei[egc];
            const float4* xr = (const float4*)(x + (size_t)s * IN_CHN + q * 16);
            #pragma unroll
            for (int i = 0; i < 4; ++i) {
                float4 v = xr[i];
                int k = q * 16 + i * 4;
                msg[(k + 0) * MPAD + el] = v.x;
                msg[(k + 1) * MPAD + el] = v.y;
                msg[(k + 2) * MPAD + el] = v.z;
                msg[(k + 3) * MPAD + el] = v.w;
            }
            // time encoding: j = q*4 .. q*4+3 of 32 freqs
            float t = et[egc];
            #pragma unroll
            for (int jj = 0; jj < 4; ++jj) {
                int j = q * 4 + jj;
                float ang = t * freqs[j] * 6.283185307179586f;
                msg[(IN_CHN + j)      * MPAD + el] = __sinf(ang);
                msg[(IN_CHN + 32 + j) * MPAD + el] = __cosf(ang);
            }
        }
        __syncthreads();

        // ---- compute: 4 edges x 4 channels per thread ----
        float acc[4][4];
        #pragma unroll
        for (int m = 0; m < 4; ++m)
            #pragma unroll
            for (int c = 0; c < 4; ++c) acc[m][c] = 0.0f;

        #pragma unroll 4
        for (int k = 0; k < KD; ++k) {
            float4 av = *(const float4*)&msg[k * MPAD + ty * 4];
            float4 bv = *(const float4*)&Wt[(k << 7) + (tx << 2)];
            float am[4] = {av.x, av.y, av.z, av.w};
            float bc[4] = {bv.x, bv.y, bv.z, bv.w};
            #pragma unroll
            for (int m = 0; m < 4; ++m)
                #pragma unroll
                for (int c = 0; c < 4; ++c)
                    acc[m][c] = fmaf(am[m], bc[c], acc[m][c]);
        }

        // ---- epilogue: tanh, alpha reduce, bf16 store, atomicMax ----
        const float4 bb = *(const float4*)(lb + tx * 4);
        const float4 aa = *(const float4*)(attn + tx * 4);
        #pragma unroll
        for (int m = 0; m < 4; ++m) {
            int e = e0 + ty * 4 + m;
            float h0 = tanhf(acc[m][0] + bb.x);
            float h1 = tanhf(acc[m][1] + bb.y);
            float h2 = tanhf(acc[m][2] + bb.z);
            float h3 = tanhf(acc[m][3] + bb.w);
            float al = h0 * aa.x + h1 * aa.y + h2 * aa.z + h3 * aa.w;
            #pragma unroll
            for (int off = 16; off > 0; off >>= 1)
                al += __shfl_xor(al, off);
            if (e < E) {
                ushort4 hv;
                hv.x = f2bf(h0); hv.y = f2bf(h1); hv.z = f2bf(h2); hv.w = f2bf(h3);
                *(ushort4*)(h_ws + (size_t)e * OUT_CHN + tx * 4) = hv;
                if (tx == 0) {
                    alpha[e] = al;
                    int d = ei[E + e];
                    atomicMaxF(&node_max[d], al);
                }
            }
        }
    }
}

__global__ __launch_bounds__(256) void exp_denom(
    const float* __restrict__ alpha, const int* __restrict__ ei,
    const float* __restrict__ nm, float* __restrict__ ex,
    float* __restrict__ den, int E)
{
    int e = blockIdx.x * 256 + threadIdx.x;
    if (e < E) {
        int d = ei[E + e];
        float v = expf(alpha[e] - nm[d]);
        ex[e] = v;
        atomicAdd(den + d, v);
    }
}

__global__ __launch_bounds__(256) void scatter(
    const unsigned short* __restrict__ h_ws, const float* __restrict__ ex,
    const float* __restrict__ den, const int* __restrict__ ei,
    float* __restrict__ out, int E)
{
    long long gid = (long long)blockIdx.x * 256 + threadIdx.x;
    int e = (int)(gid >> 5);
    if (e >= E) return;
    int c0 = ((int)gid & 31) * 4;
    int d = ei[E + e];
    float w = ex[e] / (den[d] + 1e-16f);
    ushort4 hv = *(const ushort4*)(h_ws + (size_t)e * OUT_CHN + c0);
    float* op = out + (size_t)d * OUT_CHN + c0;
    atomicAdd(op + 0, bf2f(hv.x) * w);
    atomicAdd(op + 1, bf2f(hv.y) * w);
    atomicAdd(op + 2, bf2f(hv.z) * w);
    atomicAdd(op + 3, bf2f(hv.w) * w);
}

extern "C" void kernel_launch(void* const* d_in, const int* in_sizes, int n_in,
                              void* d_out, int out_size, void* d_ws, size_t ws_size,
                              hipStream_t stream) {
    const float* x     = (const float*)d_in[0];
    const int*   ei    = (const int*)d_in[1];     // [2, E] int32
    const float* et    = (const float*)d_in[2];
    const float* freqs = (const float*)d_in[3];
    const float* lw    = (const float*)d_in[4];   // [128, 192]
    const float* lb    = (const float*)d_in[5];
    const float* attn  = (const float*)d_in[6];
    float* out = (float*)d_out;

    const int E = in_sizes[2];
    const int Nn = in_sizes[0] / IN_CHN;

    // workspace layout
    char* ws = (char*)d_ws;
    unsigned short* h_ws = (unsigned short*)ws;               // E*128 bf16
    size_t off = (size_t)E * OUT_CHN * sizeof(unsigned short);
    float* alpha = (float*)(ws + off); off += (size_t)E * sizeof(float);
    float* ex    = (float*)(ws + off); off += (size_t)E * sizeof(float);
    float* nm    = (float*)(ws + off); off += (size_t)Nn * sizeof(float);
    float* den   = (float*)(ws + off);

    hipMemsetAsync(d_out, 0, (size_t)out_size * sizeof(float), stream);
    init_nodes<<<(Nn + 255) / 256, 256, 0, stream>>>(nm, den, Nn);

    const int n_tiles = (E + TM - 1) / TM;
    gemm_alpha<<<256, 256, 0, stream>>>(x, ei, et, freqs, lw, lb, attn,
                                        h_ws, alpha, nm, E, n_tiles);
    exp_denom<<<(E + 255) / 256, 256, 0, stream>>>(alpha, ei, nm, ex, den, E);

    long long sth = (long long)E * 32;
    scatter<<<(unsigned)((sth + 255) / 256), 256, 0, stream>>>(h_ws, ex, den, ei, out, E);
}

// Round 2
// 1149.744 us; speedup vs baseline: 2.1698x; 2.1698x over previous
//
#include <hip/hip_runtime.h>
#include <hip/hip_bf16.h>
#include <math.h>

#define IN_CHN 128
#define OUT_CHN 128
#define TDIM 64
#define KD 192        // IN_CHN + TDIM
#define TM 32         // edges per tile
#define MPAD 36       // padded stride (floats): 144 B, 16B-aligned rows

static __device__ __forceinline__ unsigned short f2bf(float f) {
    unsigned int u = __float_as_uint(f);
    unsigned int r = (u + 0x7FFFu + ((u >> 16) & 1u)) >> 16;  // RNE
    return (unsigned short)r;
}
static __device__ __forceinline__ float bf2f(unsigned short b) {
    return __uint_as_float(((unsigned int)b) << 16);
}

// ---------------- CSR build ----------------

__global__ __launch_bounds__(256) void zero_deg(int* deg, int n) {
    int i = blockIdx.x * 256 + threadIdx.x;
    if (i < n) deg[i] = 0;
}

__global__ __launch_bounds__(256) void count_deg(const int* __restrict__ ei,
                                                 int* __restrict__ deg, int E) {
    int e = blockIdx.x * 256 + threadIdx.x;
    if (e < E) atomicAdd(&deg[ei[E + e]], 1);
}

static __device__ __forceinline__ int wave_incl_scan(int v, int lane) {
    #pragma unroll
    for (int off = 1; off < 64; off <<= 1) {
        int t = __shfl_up(v, off);
        if (lane >= off) v += t;
    }
    return v;
}

// per-block exclusive scan of deg -> offs (block-local), block total -> partial[bid]
__global__ __launch_bounds__(256) void scan_local(const int* __restrict__ deg,
    int* __restrict__ offs, int* __restrict__ partial, int Nn)
{
    __shared__ int wsum[4];
    int tid = threadIdx.x, lane = tid & 63, wid = tid >> 6;
    int i = blockIdx.x * 256 + tid;
    int v = (i < Nn) ? deg[i] : 0;
    int incl = wave_incl_scan(v, lane);
    if (lane == 63) wsum[wid] = incl;
    __syncthreads();
    int wpre = 0;
    for (int w = 0; w < wid; ++w) wpre += wsum[w];
    if (i < Nn) offs[i] = wpre + incl - v;       // exclusive within block
    if (tid == 255) partial[blockIdx.x] = wpre + incl;  // block total
}

// single-block exclusive scan of block partials (nparts <= 256)
__global__ __launch_bounds__(256) void scan_partial(int* __restrict__ partial, int nparts)
{
    __shared__ int wsum[4];
    int tid = threadIdx.x, lane = tid & 63, wid = tid >> 6;
    int v = (tid < nparts) ? partial[tid] : 0;
    int incl = wave_incl_scan(v, lane);
    if (lane == 63) wsum[wid] = incl;
    __syncthreads();
    int wpre = 0;
    for (int w = 0; w < wid; ++w) wpre += wsum[w];
    if (tid < nparts) partial[tid] = wpre + incl - v;   // exclusive
}

__global__ __launch_bounds__(256) void finalize_offs(int* __restrict__ offs,
    const int* __restrict__ partial, int* __restrict__ cursor, int Nn)
{
    int i = blockIdx.x * 256 + threadIdx.x;
    if (i < Nn) { int o = offs[i] + partial[i >> 8]; offs[i] = o; cursor[i] = o; }
}

__global__ __launch_bounds__(256) void fill_bucket(const int* __restrict__ ei,
    int* __restrict__ cursor, int* __restrict__ bucket, int E)
{
    int e = blockIdx.x * 256 + threadIdx.x;
    if (e < E) {
        int d = ei[E + e];
        int pos = atomicAdd(&cursor[d], 1);
        bucket[pos] = e;
    }
}

// ---------------- GEMM + alpha ----------------
// Persistent-block GEMM: h = tanh([x[src], te] @ W^T + b), alpha = h . attn

__global__ __launch_bounds__(256) void gemm_alpha(
    const float* __restrict__ x, const int* __restrict__ ei,
    const float* __restrict__ et, const float* __restrict__ freqs,
    const float* __restrict__ lw, const float* __restrict__ lb,
    const float* __restrict__ attn,
    unsigned short* __restrict__ h_ws, float* __restrict__ alpha,
    int E, int n_tiles)
{
    __shared__ float smem[24576 + KD * MPAD];   // 125,952 B
    float* Wt  = smem;          // Wt[k][c] = lw[c][k], [192][128]
    float* msg = smem + 24576;  // msg[k][edge], [192][36]

    const int tid = threadIdx.x;

    for (int i = tid; i < 24576; i += 256) {
        int k = i >> 7, c = i & 127;
        Wt[i] = lw[c * KD + k];
    }

    const int tx = tid & 31;        // channel group: c0 = tx*4
    const int ty = tid >> 5;        // edge group:    m0 = ty*4

    for (int tile = blockIdx.x; tile < n_tiles; tile += gridDim.x) {
        const int e0 = tile * TM;
        __syncthreads();   // msg readers from previous tile done

        {
            const int el = tid & 31;
            const int q  = tid >> 5;
            int eg = e0 + el;
            int egc = eg < E ? eg : E - 1;
            int s = ei[egc];
            const float4* xr = (const float4*)(x + (size_t)s * IN_CHN + q * 16);
            #pragma unroll
            for (int i = 0; i < 4; ++i) {
                float4 v = xr[i];
                int k = q * 16 + i * 4;
                msg[(k + 0) * MPAD + el] = v.x;
                msg[(k + 1) * MPAD + el] = v.y;
                msg[(k + 2) * MPAD + el] = v.z;
                msg[(k + 3) * MPAD + el] = v.w;
            }
            float t = et[egc];
            #pragma unroll
            for (int jj = 0; jj < 4; ++jj) {
                int j = q * 4 + jj;
                float ang = t * freqs[j] * 6.283185307179586f;
                msg[(IN_CHN + j)      * MPAD + el] = __sinf(ang);
                msg[(IN_CHN + 32 + j) * MPAD + el] = __cosf(ang);
            }
        }
        __syncthreads();

        float acc[4][4];
        #pragma unroll
        for (int m = 0; m < 4; ++m)
            #pragma unroll
            for (int c = 0; c < 4; ++c) acc[m][c] = 0.0f;

        #pragma unroll 4
        for (int k = 0; k < KD; ++k) {
            float4 av = *(const float4*)&msg[k * MPAD + ty * 4];
            float4 bv = *(const float4*)&Wt[(k << 7) + (tx << 2)];
            float am[4] = {av.x, av.y, av.z, av.w};
            float bc[4] = {bv.x, bv.y, bv.z, bv.w};
            #pragma unroll
            for (int m = 0; m < 4; ++m)
                #pragma unroll
                for (int c = 0; c < 4; ++c)
                    acc[m][c] = fmaf(am[m], bc[c], acc[m][c]);
        }

        const float4 bb = *(const float4*)(lb + tx * 4);
        const float4 aa = *(const float4*)(attn + tx * 4);
        #pragma unroll
        for (int m = 0; m < 4; ++m) {
            int e = e0 + ty * 4 + m;
            float h0 = tanhf(acc[m][0] + bb.x);
            float h1 = tanhf(acc[m][1] + bb.y);
            float h2 = tanhf(acc[m][2] + bb.z);
            float h3 = tanhf(acc[m][3] + bb.w);
            float al = h0 * aa.x + h1 * aa.y + h2 * aa.z + h3 * aa.w;
            #pragma unroll
            for (int off = 16; off > 0; off >>= 1)
                al += __shfl_xor(al, off);
            if (e < E) {
                ushort4 hv;
                hv.x = f2bf(h0); hv.y = f2bf(h1); hv.z = f2bf(h2); hv.w = f2bf(h3);
                *(ushort4*)(h_ws + (size_t)e * OUT_CHN + tx * 4) = hv;
                if (tx == 0) alpha[e] = al;
            }
        }
    }
}

// ---------------- per-node aggregation (one wave per node) ----------------

__global__ __launch_bounds__(256) void agg(
    const unsigned short* __restrict__ h_ws, const float* __restrict__ alpha,
    const int* __restrict__ bucket, const int* __restrict__ offs,
    const int* __restrict__ deg, float* __restrict__ out, int Nn)
{
    int wid  = threadIdx.x >> 6;
    int lane = threadIdx.x & 63;
    int node = blockIdx.x * 4 + wid;
    if (node >= Nn) return;
    int start = offs[node];
    int d = deg[node];
    float* op = out + (size_t)node * OUT_CHN + lane * 2;
    if (d == 0) { op[0] = 0.0f; op[1] = 0.0f; return; }

    // pass 1a: segment max (order-independent)
    float m = -INFINITY;
    for (int i = lane; i < d; i += 64) m = fmaxf(m, alpha[bucket[start + i]]);
    #pragma unroll
    for (int off = 32; off > 0; off >>= 1) m = fmaxf(m, __shfl_xor(m, off));

    // pass 1b: exp-sum
    float s = 0.0f;
    for (int i = lane; i < d; i += 64) s += expf(alpha[bucket[start + i]] - m);
    #pragma unroll
    for (int off = 32; off > 0; off >>= 1) s += __shfl_xor(s, off);
    float rs = 1.0f / (s + 1e-16f);

    // pass 2: weighted sum of h rows; lane owns channels {2*lane, 2*lane+1}
    float a0 = 0.0f, a1 = 0.0f;
    for (int i = 0; i < d; ++i) {
        int e = bucket[start + i];
        float w = expf(alpha[e] - m) * rs;
        unsigned int hv = *(const unsigned int*)(h_ws + (size_t)e * OUT_CHN + lane * 2);
        a0 = fmaf(__uint_as_float((hv & 0xFFFFu) << 16), w, a0);
        a1 = fmaf(__uint_as_float((hv >> 16) << 16), w, a1);
    }
    op[0] = a0; op[1] = a1;
}

// ---------------- launch ----------------

extern "C" void kernel_launch(void* const* d_in, const int* in_sizes, int n_in,
                              void* d_out, int out_size, void* d_ws, size_t ws_size,
                              hipStream_t stream) {
    const float* x     = (const float*)d_in[0];
    const int*   ei    = (const int*)d_in[1];     // [2, E]
    const float* et    = (const float*)d_in[2];
    const float* freqs = (const float*)d_in[3];
    const float* lw    = (const float*)d_in[4];   // [128, 192]
    const float* lb    = (const float*)d_in[5];
    const float* attn  = (const float*)d_in[6];
    float* out = (float*)d_out;

    const int E  = in_sizes[2];
    const int Nn = in_sizes[0] / IN_CHN;

    // workspace layout
    char* ws = (char*)d_ws;
    unsigned short* h_ws = (unsigned short*)ws;               // E*128 bf16
    size_t off = (size_t)E * OUT_CHN * sizeof(unsigned short);
    float* alpha  = (float*)(ws + off); off += (size_t)E * sizeof(float);
    int*   bucket = (int*)(ws + off);   off += (size_t)E * sizeof(int);
    int*   deg    = (int*)(ws + off);   off += (size_t)Nn * sizeof(int);
    int*   offs   = (int*)(ws + off);   off += (size_t)Nn * sizeof(int);
    int*   cursor = (int*)(ws + off);   off += (size_t)Nn * sizeof(int);
    int*   partial= (int*)(ws + off);

    const int nblk  = (Nn + 255) / 256;   // 196
    const int eblk  = (E + 255) / 256;    // 3125

    // CSR build
    zero_deg<<<nblk, 256, 0, stream>>>(deg, Nn);
    count_deg<<<eblk, 256, 0, stream>>>(ei, deg, E);
    scan_local<<<nblk, 256, 0, stream>>>(deg, offs, partial, Nn);
    scan_partial<<<1, 256, 0, stream>>>(partial, nblk);
    finalize_offs<<<nblk, 256, 0, stream>>>(offs, partial, cursor, Nn);
    fill_bucket<<<eblk, 256, 0, stream>>>(ei, cursor, bucket, E);

    // GEMM + alpha
    const int n_tiles = (E + TM - 1) / TM;
    gemm_alpha<<<256, 256, 0, stream>>>(x, ei, et, freqs, lw, lb, attn,
                                        h_ws, alpha, E, n_tiles);

    // per-node softmax + weighted aggregation
    agg<<<(Nn + 3) / 4, 256, 0, stream>>>(h_ws, alpha, bucket, offs, deg, out, Nn);
}

// Round 3
// 349.080 us; speedup vs baseline: 7.1467x; 3.2936x over previous
//
#include <hip/hip_runtime.h>
#include <hip/hip_bf16.h>
#include <math.h>

#define IN_CHN 128
#define OUT_CHN 128
#define KD 192
#define TM 64                  // edges per tile
#define MS 216                 // msg row stride in ushorts (432 B: 16B-aligned, 2-way-free banks)

typedef __bf16 bf16x8 __attribute__((ext_vector_type(8)));
typedef float f32x4 __attribute__((ext_vector_type(4)));

static __device__ __forceinline__ unsigned short f2b(float f) {
    return __builtin_bit_cast(unsigned short, (__bf16)f);   // RNE
}
static __device__ __forceinline__ float b2f(unsigned short b) {
    return __uint_as_float(((unsigned int)b) << 16);
}
static __device__ __forceinline__ float fast_tanh(float x) {
    float e = __expf(2.0f * x);
    return 1.0f - 2.0f * __builtin_amdgcn_rcpf(e + 1.0f);
}

// ---------------- CSR build ----------------

__global__ __launch_bounds__(256) void zero_deg(int* deg, int n) {
    int i = blockIdx.x * 256 + threadIdx.x;
    if (i < n) deg[i] = 0;
}

__global__ __launch_bounds__(256) void count_deg(const int* __restrict__ ei,
                                                 int* __restrict__ deg, int E) {
    int e = blockIdx.x * 256 + threadIdx.x;
    if (e < E) atomicAdd(&deg[ei[E + e]], 1);
}

static __device__ __forceinline__ int wave_incl_scan(int v, int lane) {
    #pragma unroll
    for (int off = 1; off < 64; off <<= 1) {
        int t = __shfl_up(v, off);
        if (lane >= off) v += t;
    }
    return v;
}

__global__ __launch_bounds__(256) void scan_local(const int* __restrict__ deg,
    int* __restrict__ offs, int* __restrict__ partial, int Nn)
{
    __shared__ int wsum[4];
    int tid = threadIdx.x, lane = tid & 63, wid = tid >> 6;
    int i = blockIdx.x * 256 + tid;
    int v = (i < Nn) ? deg[i] : 0;
    int incl = wave_incl_scan(v, lane);
    if (lane == 63) wsum[wid] = incl;
    __syncthreads();
    int wpre = 0;
    for (int w = 0; w < wid; ++w) wpre += wsum[w];
    if (i < Nn) offs[i] = wpre + incl - v;
    if (tid == 255) partial[blockIdx.x] = wpre + incl;
}

__global__ __launch_bounds__(256) void scan_partial(int* __restrict__ partial, int nparts)
{
    __shared__ int wsum[4];
    int tid = threadIdx.x, lane = tid & 63, wid = tid >> 6;
    int v = (tid < nparts) ? partial[tid] : 0;
    int incl = wave_incl_scan(v, lane);
    if (lane == 63) wsum[wid] = incl;
    __syncthreads();
    int wpre = 0;
    for (int w = 0; w < wid; ++w) wpre += wsum[w];
    if (tid < nparts) partial[tid] = wpre + incl - v;
}

__global__ __launch_bounds__(256) void finalize_offs(int* __restrict__ offs,
    const int* __restrict__ partial, int* __restrict__ cursor, int Nn)
{
    int i = blockIdx.x * 256 + threadIdx.x;
    if (i < Nn) { int o = offs[i] + partial[i >> 8]; offs[i] = o; cursor[i] = o; }
}

// scatter src/t into CSR-permuted order (edge order within a bucket is
// race-dependent but softmax is order-insensitive to fp tolerance)
__global__ __launch_bounds__(256) void fill_perm(const int* __restrict__ ei,
    const float* __restrict__ et, int* __restrict__ cursor,
    int* __restrict__ srcp, float* __restrict__ etp, int E)
{
    int e = blockIdx.x * 256 + threadIdx.x;
    if (e < E) {
        int d = ei[E + e];
        int pos = atomicAdd(&cursor[d], 1);
        srcp[pos] = ei[e];
        etp[pos] = et[e];
    }
}

// ---------------- MFMA GEMM + alpha ----------------
// h = tanh([x[src], te(t)] @ W^T + b), alpha = h . attn, edges in CSR order.
// Per block: 4 waves; tile = 64 edges x 128 ch; W frags in registers.
// MFMA D: row = channel (lane>>4)*4+reg within nf-block, col = edge (lane&15).

__global__ __launch_bounds__(256) void gemm_mfma(
    const float* __restrict__ x, const int* __restrict__ srcp,
    const float* __restrict__ etp, const float* __restrict__ freqs,
    const float* __restrict__ lw, const float* __restrict__ lb,
    const float* __restrict__ attn,
    unsigned short* __restrict__ h_p, float* __restrict__ alpha_p,
    int E, int n_tiles)
{
    __shared__ unsigned short msg[TM * MS];   // 27648 B
    __shared__ float alpha_s[TM];

    const int tid  = threadIdx.x;
    const int lane = tid & 63;
    const int wv   = tid >> 6;          // wave 0..3
    const int c16  = lane & 15;
    const int g    = lane >> 4;         // 0..3
    const int wbase = wv * 32;          // this wave's channel base

    // W fragments, persistent in registers: Wf[kk][nf]
    // lane's col = wbase + nf*16 + c16 ; k = kk*32 + g*8 + j
    bf16x8 Wf[6][2];
    #pragma unroll
    for (int kk = 0; kk < 6; ++kk)
        #pragma unroll
        for (int nf = 0; nf < 2; ++nf) {
            const float* wp = lw + (size_t)(wbase + nf * 16 + c16) * KD + kk * 32 + g * 8;
            float4 v0 = *(const float4*)wp;
            float4 v1 = *(const float4*)(wp + 4);
            bf16x8 b;
            b[0] = (__bf16)v0.x; b[1] = (__bf16)v0.y; b[2] = (__bf16)v0.z; b[3] = (__bf16)v0.w;
            b[4] = (__bf16)v1.x; b[5] = (__bf16)v1.y; b[6] = (__bf16)v1.z; b[7] = (__bf16)v1.w;
            Wf[kk][nf] = b;
        }

    // bias/attn for this lane's output channels: wbase + nf*16 + g*4 + r
    f32x4 bias_v[2], attn_v[2];
    #pragma unroll
    for (int nf = 0; nf < 2; ++nf) {
        bias_v[nf] = *(const f32x4*)(lb   + wbase + nf * 16 + g * 4);
        attn_v[nf] = *(const f32x4*)(attn + wbase + nf * 16 + g * 4);
    }

    const int srow = tid >> 2;          // staging row 0..63
    const int sq   = tid & 3;           // staging quarter
    float frv[8];
    #pragma unroll
    for (int j = 0; j < 8; ++j) frv[j] = freqs[sq * 8 + j];

    for (int tile = blockIdx.x; tile < n_tiles; tile += gridDim.x) {
        const int e0 = tile * TM;
        __syncthreads();                 // prev copy-out complete

        // ---- stage msg tile (bf16) ----
        {
            int e  = e0 + srow;
            int ec = e < E ? e : E - 1;
            int s  = srcp[ec];
            float t = etp[ec];
            const float4* xr = (const float4*)(x + (size_t)s * IN_CHN + sq * 32);
            unsigned short* mrow = msg + srow * MS;
            #pragma unroll
            for (int i = 0; i < 8; ++i) {
                float4 v = xr[i];
                ushort4 pv = { f2b(v.x), f2b(v.y), f2b(v.z), f2b(v.w) };
                *(ushort4*)(mrow + sq * 32 + i * 4) = pv;
            }
            #pragma unroll
            for (int j = 0; j < 8; ++j) {
                float ang = t * frv[j] * 6.283185307179586f;
                mrow[IN_CHN + sq * 8 + j]      = f2b(__sinf(ang));
                mrow[IN_CHN + 32 + sq * 8 + j] = f2b(__cosf(ang));
            }
            if (tid < TM) alpha_s[tid] = 0.0f;
        }
        __syncthreads();

        // ---- MFMA: 6 k-steps x 4 m-frags x 2 n-frags ----
        f32x4 acc[4][2];
        #pragma unroll
        for (int mi = 0; mi < 4; ++mi) {
            acc[mi][0] = (f32x4){0.f, 0.f, 0.f, 0.f};
            acc[mi][1] = (f32x4){0.f, 0.f, 0.f, 0.f};
        }
        #pragma unroll
        for (int kk = 0; kk < 6; ++kk) {
            #pragma unroll
            for (int mi = 0; mi < 4; ++mi) {
                const unsigned short* ap = msg + (mi * 16 + c16) * MS + kk * 32 + g * 8;
                bf16x8 a = __builtin_bit_cast(bf16x8, *(const uint4*)ap);
                acc[mi][0] = __builtin_amdgcn_mfma_f32_16x16x32_bf16(Wf[kk][0], a, acc[mi][0], 0, 0, 0);
                acc[mi][1] = __builtin_amdgcn_mfma_f32_16x16x32_bf16(Wf[kk][1], a, acc[mi][1], 0, 0, 0);
            }
        }

        // ---- epilogue: tanh, alpha partials (no msg writes yet) ----
        float pal[4];
        #pragma unroll
        for (int mi = 0; mi < 4; ++mi) {
            float p = 0.0f;
            #pragma unroll
            for (int nf = 0; nf < 2; ++nf) {
                f32x4 z = acc[mi][nf];
                #pragma unroll
                for (int r = 0; r < 4; ++r) {
                    float h = fast_tanh(z[r] + bias_v[nf][r]);
                    z[r] = h;
                    p = fmaf(h, attn_v[nf][r], p);
                }
                acc[mi][nf] = z;
            }
            p += __shfl_xor(p, 16);
            p += __shfl_xor(p, 32);
            pal[mi] = p;
        }
        if (g == 0) {
            #pragma unroll
            for (int mi = 0; mi < 4; ++mi)
                atomicAdd(&alpha_s[mi * 16 + c16], pal[mi]);
        }
        __syncthreads();   // all msg reads + alpha atomics done

        // ---- pack h into msg as bf16 [row][col] ----
        #pragma unroll
        for (int mi = 0; mi < 4; ++mi)
            #pragma unroll
            for (int nf = 0; nf < 2; ++nf) {
                f32x4 h = acc[mi][nf];
                ushort4 pv = { f2b(h[0]), f2b(h[1]), f2b(h[2]), f2b(h[3]) };
                *(ushort4*)(msg + (mi * 16 + c16) * MS + wbase + nf * 16 + g * 4) = pv;
            }
        __syncthreads();

        // ---- coalesced copy-out ----
        {
            int e = e0 + srow;
            if (e < E) {
                const unsigned short* sp = msg + srow * MS + sq * 32;
                uint4* dst = (uint4*)(h_p + (size_t)e * OUT_CHN + sq * 32);
                #pragma unroll
                for (int i = 0; i < 4; ++i)
                    dst[i] = *(const uint4*)(sp + i * 8);
                if (sq == 0) alpha_p[e] = alpha_s[srow];
            }
        }
    }
}

// ---------------- per-node aggregation (one wave per node) ----------------

__global__ __launch_bounds__(256) void agg(
    const unsigned short* __restrict__ h_p, const float* __restrict__ alpha_p,
    const int* __restrict__ offs, const int* __restrict__ deg,
    float* __restrict__ out, int Nn)
{
    int wid  = threadIdx.x >> 6;
    int lane = threadIdx.x & 63;
    int node = blockIdx.x * 4 + wid;
    if (node >= Nn) return;
    int start = offs[node];
    int d = deg[node];
    float* op = out + (size_t)node * OUT_CHN + lane * 2;
    if (d == 0) { op[0] = 0.0f; op[1] = 0.0f; return; }

    float m = -INFINITY;
    for (int i = lane; i < d; i += 64) m = fmaxf(m, alpha_p[start + i]);
    #pragma unroll
    for (int off = 32; off > 0; off >>= 1) m = fmaxf(m, __shfl_xor(m, off));

    float s = 0.0f;
    for (int i = lane; i < d; i += 64) s += __expf(alpha_p[start + i] - m);
    #pragma unroll
    for (int off = 32; off > 0; off >>= 1) s += __shfl_xor(s, off);
    float rs = __builtin_amdgcn_rcpf(s + 1e-16f);

    float a0 = 0.0f, a1 = 0.0f;
    for (int i = 0; i < d; ++i) {
        float w = __expf(alpha_p[start + i] - m) * rs;
        unsigned int hv = *(const unsigned int*)(h_p + (size_t)(start + i) * OUT_CHN + lane * 2);
        a0 = fmaf(b2f((unsigned short)(hv & 0xFFFFu)), w, a0);
        a1 = fmaf(b2f((unsigned short)(hv >> 16)), w, a1);
    }
    op[0] = a0; op[1] = a1;
}

// ---------------- launch ----------------

extern "C" void kernel_launch(void* const* d_in, const int* in_sizes, int n_in,
                              void* d_out, int out_size, void* d_ws, size_t ws_size,
                              hipStream_t stream) {
    const float* x     = (const float*)d_in[0];
    const int*   ei    = (const int*)d_in[1];     // [2, E]
    const float* et    = (const float*)d_in[2];
    const float* freqs = (const float*)d_in[3];
    const float* lw    = (const float*)d_in[4];   // [128, 192]
    const float* lb    = (const float*)d_in[5];
    const float* attn  = (const float*)d_in[6];
    float* out = (float*)d_out;

    const int E  = in_sizes[2];
    const int Nn = in_sizes[0] / IN_CHN;

    // workspace layout
    char* ws = (char*)d_ws;
    unsigned short* h_p = (unsigned short*)ws;                // E*128 bf16 (perm order)
    size_t off = (size_t)E * OUT_CHN * sizeof(unsigned short);
    float* alpha_p = (float*)(ws + off); off += (size_t)E * sizeof(float);
    int*   srcp    = (int*)(ws + off);   off += (size_t)E * sizeof(int);
    float* etp     = (float*)(ws + off); off += (size_t)E * sizeof(float);
    int*   deg     = (int*)(ws + off);   off += (size_t)Nn * sizeof(int);
    int*   offs    = (int*)(ws + off);   off += (size_t)Nn * sizeof(int);
    int*   cursor  = (int*)(ws + off);   off += (size_t)Nn * sizeof(int);
    int*   partial = (int*)(ws + off);

    const int nblk = (Nn + 255) / 256;
    const int eblk = (E + 255) / 256;

    zero_deg<<<nblk, 256, 0, stream>>>(deg, Nn);
    count_deg<<<eblk, 256, 0, stream>>>(ei, deg, E);
    scan_local<<<nblk, 256, 0, stream>>>(deg, offs, partial, Nn);
    scan_partial<<<1, 256, 0, stream>>>(partial, nblk);
    finalize_offs<<<nblk, 256, 0, stream>>>(offs, partial, cursor, Nn);
    fill_perm<<<eblk, 256, 0, stream>>>(ei, et, cursor, srcp, etp, E);

    const int n_tiles = (E + TM - 1) / TM;
    gemm_mfma<<<768, 256, 0, stream>>>(x, srcp, etp, freqs, lw, lb, attn,
                                       h_p, alpha_p, E, n_tiles);

    agg<<<(Nn + 3) / 4, 256, 0, stream>>>(h_p, alpha_p, offs, deg, out, Nn);
}